// Round 1
// baseline (280.089 us; speedup 1.0000x reference)
//
#include <hip/hip_runtime.h>

#define BATCH  262144
#define NDEP   16
#define NIND   32
#define NINT   32
#define FEPS   1e-7f
#define NITER  6

__launch_bounds__(256, 3)
__global__ void clefo_kernel(const float* __restrict__ X,
                             const float* __restrict__ Z,
                             const float* __restrict__ Ups,
                             const float* __restrict__ Bmat,
                             const float* __restrict__ Theta,
                             const float* __restrict__ Gamma,
                             const float* __restrict__ Lam,
                             float* __restrict__ Y) {
    // Weights staged transposed in LDS: column j of the [16 x K] matrices is
    // contiguous so the fully-unrolled i-loops read 16 consecutive floats
    // (wave-uniform address -> ds_read_b128 broadcast, conflict-free).
    __shared__ float sBt[NIND][NDEP];   // sBt[j][i] = Bmat[i][j]
    __shared__ float sTt[NINT][NDEP];   // sTt[j][i] = Theta[i][j]
    __shared__ float sLt[NIND][NDEP];   // sLt[j][i] = Lam[i][j]
    __shared__ float sOt[NDEP][NDEP];   // sOt[j][i] = (i==j) ? 0 : Gamma[i][j]
    __shared__ float sC[NDEP];          // 1+eps - Gamma[i][i]
    __shared__ float sU[NDEP];          // Upsilon

    const int tid = threadIdx.x;

    for (int t = tid; t < NDEP * NIND; t += 256) {
        const int i = t >> 5;           // row (dep)
        const int j = t & 31;           // col (indep/inter)
        sBt[j][i] = Bmat[t];
        sTt[j][i] = Theta[t];
        sLt[j][i] = Lam[t];
    }
    if (tid < NDEP * NDEP) {
        const int i = tid >> 4;
        const int j = tid & 15;
        sOt[j][i] = (i == j) ? 0.0f : Gamma[tid];
    }
    if (tid < NDEP) {
        sC[tid] = 1.0f + FEPS - Gamma[tid * NDEP + tid];
        sU[tid] = Ups[tid];
    }
    __syncthreads();

    const int b = blockIdx.x * 256 + tid;

    // Coalesced-ish vector loads: 16B/lane, whole wave covers a contiguous
    // 8KB region across its 16 loads -> every fetched byte is consumed.
    const float4* Xv = (const float4*)(X + (size_t)b * NIND);
    const float4* Zv = (const float4*)(Z + (size_t)b * NINT);
    float x[NIND], z[NINT];
    #pragma unroll
    for (int q = 0; q < NIND / 4; ++q) {
        float4 v = Xv[q];
        x[4*q+0] = v.x; x[4*q+1] = v.y; x[4*q+2] = v.z; x[4*q+3] = v.w;
    }
    #pragma unroll
    for (int q = 0; q < NINT / 4; ++q) {
        float4 v = Zv[q];
        z[4*q+0] = v.x; z[4*q+1] = v.y; z[4*q+2] = v.z; z[4*q+3] = v.w;
    }

    // rhs = Ups + Bmat @ x + Theta @ z ;  d = Lam @ x
    float rhs[NDEP], d[NDEP];
    #pragma unroll
    for (int i = 0; i < NDEP; ++i) { rhs[i] = sU[i]; d[i] = 0.0f; }

    #pragma unroll
    for (int j = 0; j < NIND; ++j) {
        const float xj = x[j];
        #pragma unroll
        for (int i = 0; i < NDEP; ++i) {
            rhs[i] = fmaf(sBt[j][i], xj, rhs[i]);
            d[i]   = fmaf(sLt[j][i], xj, d[i]);
        }
    }
    #pragma unroll
    for (int j = 0; j < NINT; ++j) {
        const float zj = z[j];
        #pragma unroll
        for (int i = 0; i < NDEP; ++i) {
            rhs[i] = fmaf(sTt[j][i], zj, rhs[i]);
        }
    }

    // A = Dg - O, Dg_i = (1+eps-Gamma_ii) - d_i, O = offdiag(Gamma).
    // Jacobi: y <- inv(Dg) * (rhs + O y). Diagonally dominant: rate <~0.29
    // worst-case -> 6 iters give ~5e-5 abs error vs 8.5e-3 threshold.
    float inv[NDEP], y[NDEP];
    #pragma unroll
    for (int i = 0; i < NDEP; ++i) {
        inv[i] = __builtin_amdgcn_rcpf(sC[i] - d[i]);
        y[i]   = rhs[i] * inv[i];
    }

    #pragma unroll
    for (int it = 0; it < NITER; ++it) {
        float t[NDEP];
        #pragma unroll
        for (int i = 0; i < NDEP; ++i) t[i] = rhs[i];
        #pragma unroll
        for (int j = 0; j < NDEP; ++j) {
            const float yj = y[j];
            #pragma unroll
            for (int i = 0; i < NDEP; ++i) {
                t[i] = fmaf(sOt[j][i], yj, t[i]);
            }
        }
        #pragma unroll
        for (int i = 0; i < NDEP; ++i) y[i] = t[i] * inv[i];
    }

    float4* Yv = (float4*)(Y + (size_t)b * NDEP);
    #pragma unroll
    for (int q = 0; q < NDEP / 4; ++q) {
        Yv[q] = make_float4(y[4*q+0], y[4*q+1], y[4*q+2], y[4*q+3]);
    }
}

extern "C" void kernel_launch(void* const* d_in, const int* in_sizes, int n_in,
                              void* d_out, int out_size, void* d_ws, size_t ws_size,
                              hipStream_t stream) {
    const float* X     = (const float*)d_in[0];
    const float* Z     = (const float*)d_in[1];
    const float* Ups   = (const float*)d_in[2];
    const float* Bmat  = (const float*)d_in[3];
    const float* Theta = (const float*)d_in[4];
    const float* Gamma = (const float*)d_in[5];
    const float* Lam   = (const float*)d_in[6];
    float* Y = (float*)d_out;

    clefo_kernel<<<BATCH / 256, 256, 0, stream>>>(X, Z, Ups, Bmat, Theta, Gamma, Lam, Y);
}

// Round 2
// 161.244 us; speedup vs baseline: 1.7371x; 1.7371x over previous
//
#include <hip/hip_runtime.h>

#define BATCH  262144
#define NDEP   16
#define NIND   32
#define NINT   32
#define FEPS   1e-7f
#define NITER  6

// Weights are read with wave-uniform constant-index accesses from __restrict__
// const pointers -> backend emits s_load (SMEM pipe, K$-hot, SGPR operand is
// free in v_fma). No LDS at all. launch_bounds(256,2) caps at 256 VGPRs so the
// ~115 live fp32 values never spill (R1: 84 VGPRs + 520 MB scratch traffic).
__launch_bounds__(256, 2)
__global__ void clefo_kernel(const float* __restrict__ X,
                             const float* __restrict__ Z,
                             const float* __restrict__ Ups,
                             const float* __restrict__ Bmat,
                             const float* __restrict__ Theta,
                             const float* __restrict__ Gamma,
                             const float* __restrict__ Lam,
                             float* __restrict__ Y) {
    const int b = blockIdx.x * 256 + threadIdx.x;

    // 16B/lane vector loads; a wave's 8 loads cover one contiguous 32KB region
    // (X) + 32KB (Z) -> every fetched line is consumed (L1-resident reuse
    // across the 4 q-iterations).
    const float4* Xv = (const float4*)(X + (size_t)b * NIND);
    const float4* Zv = (const float4*)(Z + (size_t)b * NINT);
    float x[NIND], z[NINT];
    #pragma unroll
    for (int q = 0; q < NIND / 4; ++q) {
        float4 v = Xv[q];
        x[4*q+0] = v.x; x[4*q+1] = v.y; x[4*q+2] = v.z; x[4*q+3] = v.w;
    }
    #pragma unroll
    for (int q = 0; q < NINT / 4; ++q) {
        float4 v = Zv[q];
        z[4*q+0] = v.x; z[4*q+1] = v.y; z[4*q+2] = v.z; z[4*q+3] = v.w;
    }

    // rhs = Ups + Bmat @ x + Theta @ z ;  d = Lam @ x
    // All weight reads below are uniform scalar loads.
    float rhs[NDEP], d[NDEP];
    #pragma unroll
    for (int i = 0; i < NDEP; ++i) { rhs[i] = Ups[i]; d[i] = 0.0f; }

    #pragma unroll
    for (int j = 0; j < NIND; ++j) {
        const float xj = x[j];
        const float zj = z[j];
        #pragma unroll
        for (int i = 0; i < NDEP; ++i) {
            rhs[i] = fmaf(Bmat[i * NIND + j], xj, rhs[i]);
            d[i]   = fmaf(Lam[i * NIND + j], xj, d[i]);
            rhs[i] = fmaf(Theta[i * NINT + j], zj, rhs[i]);
        }
    }

    // A = Dg - O with Dg_i = (1+eps-Gamma_ii) - d_i, O = offdiag(Gamma).
    // Jacobi: y <- inv(Dg) * (rhs + O y). Diagonal dominance: worst-case
    // contraction ~0.22 -> 6 iters gives ~1e-4 abs error vs 8.5e-3 threshold.
    float inv[NDEP], y[NDEP];
    #pragma unroll
    for (int i = 0; i < NDEP; ++i) {
        const float dg = (1.0f + FEPS - Gamma[i * NDEP + i]) - d[i];
        inv[i] = __builtin_amdgcn_rcpf(dg);
        y[i]   = rhs[i] * inv[i];
    }

    #pragma unroll
    for (int it = 0; it < NITER; ++it) {
        float t[NDEP];
        #pragma unroll
        for (int i = 0; i < NDEP; ++i) t[i] = rhs[i];
        #pragma unroll
        for (int j = 0; j < NDEP; ++j) {
            const float yj = y[j];
            #pragma unroll
            for (int i = 0; i < NDEP; ++i) {
                if (i != j) {  // compile-time: diag excluded
                    t[i] = fmaf(Gamma[i * NDEP + j], yj, t[i]);
                }
            }
        }
        #pragma unroll
        for (int i = 0; i < NDEP; ++i) y[i] = t[i] * inv[i];
    }

    float4* Yv = (float4*)(Y + (size_t)b * NDEP);
    #pragma unroll
    for (int q = 0; q < NDEP / 4; ++q) {
        Yv[q] = make_float4(y[4*q+0], y[4*q+1], y[4*q+2], y[4*q+3]);
    }
}

extern "C" void kernel_launch(void* const* d_in, const int* in_sizes, int n_in,
                              void* d_out, int out_size, void* d_ws, size_t ws_size,
                              hipStream_t stream) {
    const float* X     = (const float*)d_in[0];
    const float* Z     = (const float*)d_in[1];
    const float* Ups   = (const float*)d_in[2];
    const float* Bmat  = (const float*)d_in[3];
    const float* Theta = (const float*)d_in[4];
    const float* Gamma = (const float*)d_in[5];
    const float* Lam   = (const float*)d_in[6];
    float* Y = (float*)d_out;

    clefo_kernel<<<BATCH / 256, 256, 0, stream>>>(X, Z, Ups, Bmat, Theta, Gamma, Lam, Y);
}